// Round 1
// 1503.193 us; speedup vs baseline: 1.0280x; 1.0280x over previous
//
#include <hip/hip_runtime.h>

#define CHANNELS 1024
#define HEADS 16
#define BATCH 32
#define SEQ 8192
#define NCHUNK 16
#define TCHUNK (SEQ / NCHUNK)   // 512 rows per block

// workspace layout (in floats):
//   acc partials: [BATCH*NCHUNK][HEADS][CHANNELS]
//   l partials:   [BATCH*NCHUNK][HEADS]
//   pm:           [BATCH][CHANNELS]
#define ACC_FLOATS (BATCH * NCHUNK * HEADS * CHANNELS)
#define L_OFF      ACC_FLOATS
#define L_FLOATS   (BATCH * NCHUNK * HEADS)
#define PM_OFF     (ACC_FLOATS + L_FLOATS)

__device__ __forceinline__ float dot4(float4 a, float4 b) {
    float s = a.x * b.x;
    s = fmaf(a.y, b.y, s);
    s = fmaf(a.z, b.z, s);
    s = fmaf(a.w, b.w, s);
    return s;
}

// K1: fused scores + exp + weighted accumulation, one chunk of 512 rows per block.
// Wave w owns heads 4w..4w+3. Lane l owns channels {4l+256k : k=0..3}.
//
// Allreduce of the 4 head-partials p0..p3 over 64 lanes uses a folded butterfly:
//   step A (xor 32): fold 4 values -> 2  (A = head (g&2), B = head (g&2)|1)
//   step B (xor 16): fold 2 values -> 1  (S = head g, g = lane>>4)
//   steps xor 8/4/2/1: reduce within 16-lane group
//   ONE exp per lane (its group's head), then 3 shuffles gather all 4 exps.
// Lane's accumulator slot j holds head (g ^ j); fixed up in the store address.
// Cost/row: 10 shfl + 1 exp vs naive 24 shfl + 4 exp.
#define SCALE2 0.045084690834743236f   /* 1024^-0.5 * log2(e) */

__global__ __launch_bounds__(256, 2)
void k1_scores_acc(const float* __restrict__ x, const float* __restrict__ q,
                   float* __restrict__ ws) {
    const int tid  = threadIdx.x;
    const int lane = tid & 63;
    const int w    = tid >> 6;            // wave id -> heads 4w..4w+3
    const int b    = blockIdx.x >> 4;     // batch
    const int ck   = blockIdx.x & 15;     // chunk

    const int  cbase = 4 * lane;          // channel base for this lane
    const bool hi32  = (lane & 32) != 0;
    const bool hi16  = (lane & 16) != 0;
    const int  g     = (lane >> 4) & 3;   // lane quadrant (head permutation)

    // q fragments: qr[h][k] = q[(4w+h)][cbase + 256k .. +3]
    float4 qr[4][4];
#pragma unroll
    for (int h = 0; h < 4; ++h) {
        const float* qp = q + (4 * w + h) * CHANNELS + cbase;
#pragma unroll
        for (int k = 0; k < 4; ++k)
            qr[h][k] = *(const float4*)(qp + 256 * k);
    }

    float4 acc[4][4];
    float  l[4];
#pragma unroll
    for (int j = 0; j < 4; ++j) {
        l[j] = 0.0f;
#pragma unroll
        for (int k = 0; k < 4; ++k)
            acc[j][k] = make_float4(0.f, 0.f, 0.f, 0.f);
    }

    const float* xrow = x + (size_t)(b * SEQ + ck * TCHUNK) * CHANNELS + cbase;

#define PROCESS_ROW(XC)                                                        \
    {                                                                          \
        float p0 = dot4(XC[0], qr[0][0]); p0 += dot4(XC[1], qr[0][1]);         \
        p0 += dot4(XC[2], qr[0][2]);      p0 += dot4(XC[3], qr[0][3]);         \
        float p1 = dot4(XC[0], qr[1][0]); p1 += dot4(XC[1], qr[1][1]);         \
        p1 += dot4(XC[2], qr[1][2]);      p1 += dot4(XC[3], qr[1][3]);         \
        float p2 = dot4(XC[0], qr[2][0]); p2 += dot4(XC[1], qr[2][1]);         \
        p2 += dot4(XC[2], qr[2][2]);      p2 += dot4(XC[3], qr[2][3]);         \
        float p3 = dot4(XC[0], qr[3][0]); p3 += dot4(XC[1], qr[3][1]);         \
        p3 += dot4(XC[2], qr[3][2]);      p3 += dot4(XC[3], qr[3][3]);         \
        /* fold 4 -> 2 across the xor-32 pair */                               \
        float tA = hi32 ? p0 : p2;                                             \
        float rA = __shfl_xor(tA, 32, 64);                                     \
        float A  = (hi32 ? p2 : p0) + rA;   /* head (g&2)   */                 \
        float tB = hi32 ? p1 : p3;                                             \
        float rB = __shfl_xor(tB, 32, 64);                                     \
        float B  = (hi32 ? p3 : p1) + rB;   /* head (g&2)|1 */                 \
        /* fold 2 -> 1 across the xor-16 pair */                               \
        float tC = hi16 ? A : B;                                               \
        float rC = __shfl_xor(tC, 16, 64);                                     \
        float S  = (hi16 ? B : A) + rC;     /* head g */                       \
        /* reduce within the 16-lane group */                                  \
        S += __shfl_xor(S, 8, 64);                                             \
        S += __shfl_xor(S, 4, 64);                                             \
        S += __shfl_xor(S, 2, 64);                                             \
        S += __shfl_xor(S, 1, 64);                                             \
        /* one exp per lane, then gather the other 3 heads' exps */            \
        const float E0 = exp2f(S * SCALE2);        /* head g   */              \
        const float E1 = __shfl_xor(E0, 16, 64);   /* head g^1 */              \
        const float E2 = __shfl_xor(E0, 32, 64);   /* head g^2 */              \
        const float E3 = __shfl_xor(E1, 32, 64);   /* head g^3 */              \
        const float e[4] = {E0, E1, E2, E3};                                   \
        l[0] += E0; l[1] += E1; l[2] += E2; l[3] += E3;                        \
        _Pragma("unroll")                                                      \
        for (int j = 0; j < 4; ++j) {                                          \
            const float ev = e[j];                                             \
            _Pragma("unroll")                                                  \
            for (int k = 0; k < 4; ++k) {                                      \
                acc[j][k].x = fmaf(ev, XC[k].x, acc[j][k].x);                  \
                acc[j][k].y = fmaf(ev, XC[k].y, acc[j][k].y);                  \
                acc[j][k].z = fmaf(ev, XC[k].z, acc[j][k].z);                  \
                acc[j][k].w = fmaf(ev, XC[k].w, acc[j][k].w);                  \
            }                                                                  \
        }                                                                      \
    }

    // double-buffered row pipeline (no register copies: unrolled by 2)
    float4 xa[4], xb[4];
#pragma unroll
    for (int k = 0; k < 4; ++k)
        xa[k] = *(const float4*)(xrow + 256 * k);

    for (int r = 0; r < TCHUNK; r += 2) {
        {   // load row r+1 (always in range: TCHUNK even)
            const float* nx = xrow + (size_t)(r + 1) * CHANNELS;
#pragma unroll
            for (int k = 0; k < 4; ++k)
                xb[k] = *(const float4*)(nx + 256 * k);
        }
        PROCESS_ROW(xa)
        {   // load row r+2 (clamped on last iter; harmless L1 re-read)
            const int rn = (r + 2 < TCHUNK) ? (r + 2) : (TCHUNK - 1);
            const float* nx = xrow + (size_t)rn * CHANNELS;
#pragma unroll
            for (int k = 0; k < 4; ++k)
                xa[k] = *(const float4*)(nx + 256 * k);
        }
        PROCESS_ROW(xb)
    }
#undef PROCESS_ROW

    // write partials: slot j holds head g^j
    const int blk = b * NCHUNK + ck;
    float* accp = ws + ((size_t)(blk * HEADS + 4 * w)) * CHANNELS;
#pragma unroll
    for (int j = 0; j < 4; ++j) {
        const int h = g ^ j;
#pragma unroll
        for (int k = 0; k < 4; ++k)
            *(float4*)(accp + h * CHANNELS + cbase + 256 * k) = acc[j][k];
    }
    // lane 0 has g==0, so l[j] is head j in order; identical across the wave.
    if (lane == 0) {
        *(float4*)(ws + L_OFF + blk * HEADS + 4 * w) =
            make_float4(l[0], l[1], l[2], l[3]);
    }
}

// K2: merge chunk partials -> pm[b][c] = (1/16) * sum_h (sum_ck acc) / L[b][h]
// 8 blocks per batch (128 channels each) for 256-CU spread; 8 threads share a
// float4 column (2 chunks each), LDS tree-reduce at the end.
__global__ __launch_bounds__(256)
void k2_merge(float* __restrict__ ws) {
    const int b    = blockIdx.x >> 3;
    const int tile = blockIdx.x & 7;
    const int tid  = threadIdx.x;

    __shared__ float  lt[HEADS][NCHUNK];
    __shared__ float  linv[HEADS];
    __shared__ float4 red[8][32];

    {   // 256 threads == HEADS*NCHUNK values
        const int h = tid & 15, ck = tid >> 4;
        lt[h][ck] = ws[L_OFF + (b * NCHUNK + ck) * HEADS + h];
    }
    __syncthreads();
    if (tid < HEADS) {
        float s = 0.f;
#pragma unroll
        for (int ck = 0; ck < NCHUNK; ++ck) s += lt[tid][ck];
        linv[tid] = 1.0f / (16.0f * s);
    }
    __syncthreads();

    const int col = tid & 31;        // float4 column within this 128-ch tile
    const int sub = tid >> 5;        // 0..7 -> chunks {2*sub, 2*sub+1}
    const int c   = tile * 128 + col * 4;

    float4 pm = make_float4(0.f, 0.f, 0.f, 0.f);
#pragma unroll 1
    for (int h = 0; h < HEADS; ++h) {
        float4 hs = make_float4(0.f, 0.f, 0.f, 0.f);
#pragma unroll
        for (int d = 0; d < 2; ++d) {
            const int ck = 2 * sub + d;
            const float4 v =
                *(const float4*)(ws + ((size_t)((b * NCHUNK + ck) * HEADS + h)) * CHANNELS + c);
            hs.x += v.x; hs.y += v.y; hs.z += v.z; hs.w += v.w;
        }
        const float wi = linv[h];
        pm.x = fmaf(wi, hs.x, pm.x);
        pm.y = fmaf(wi, hs.y, pm.y);
        pm.z = fmaf(wi, hs.z, pm.z);
        pm.w = fmaf(wi, hs.w, pm.w);
    }
    red[sub][col] = pm;
    __syncthreads();
    if (tid < 32) {
        float4 s = red[0][tid];
#pragma unroll
        for (int u = 1; u < 8; ++u) {
            const float4 v = red[u][tid];
            s.x += v.x; s.y += v.y; s.z += v.z; s.w += v.w;
        }
        *(float4*)(ws + PM_OFF + b * CHANNELS + tile * 128 + tid * 4) = s;
    }
}

// K3: out[b][j] = dot(pm[b], W[j]) + bias[j].  One wave per block, 32 j's per
// block (1024 blocks): coalesced W row loads, wave-reduce, lane0 stores.
__global__ __launch_bounds__(64)
void k3_proj(const float* __restrict__ W, const float* __restrict__ bias,
             const float* __restrict__ ws, float* __restrict__ out) {
    const int lane = threadIdx.x;
    const int b  = blockIdx.x >> 5;
    const int jt = blockIdx.x & 31;   // 32 j's per block
    const int cbase = 4 * lane;

    const float* pm = ws + PM_OFF + b * CHANNELS;
    float4 pmr[4];
#pragma unroll
    for (int k = 0; k < 4; ++k)
        pmr[k] = *(const float4*)(pm + cbase + 256 * k);

#pragma unroll 2
    for (int jj = 0; jj < 32; ++jj) {
        const int j = jt * 32 + jj;
        const float* wr = W + (size_t)j * CHANNELS + cbase;
        float s = 0.f;
#pragma unroll
        for (int k = 0; k < 4; ++k)
            s += dot4(*(const float4*)(wr + 256 * k), pmr[k]);

        s += __shfl_xor(s, 32, 64);
        s += __shfl_xor(s, 16, 64);
        s += __shfl_xor(s,  8, 64);
        s += __shfl_xor(s,  4, 64);
        s += __shfl_xor(s,  2, 64);
        s += __shfl_xor(s,  1, 64);

        if (lane == 0) out[b * CHANNELS + j] = s + bias[j];
    }
}

extern "C" void kernel_launch(void* const* d_in, const int* in_sizes, int n_in,
                              void* d_out, int out_size, void* d_ws, size_t ws_size,
                              hipStream_t stream) {
    const float* x    = (const float*)d_in[0];
    const float* q    = (const float*)d_in[1];
    const float* W    = (const float*)d_in[2];
    const float* bias = (const float*)d_in[3];
    float* out = (float*)d_out;
    float* ws  = (float*)d_ws;

    k1_scores_acc<<<dim3(BATCH * NCHUNK), dim3(256), 0, stream>>>(x, q, ws);
    k2_merge<<<dim3(BATCH * 8), dim3(256), 0, stream>>>(ws);
    k3_proj<<<dim3(BATCH * 32), dim3(64), 0, stream>>>(W, bias, ws, out);
}